// Round 1
// baseline (245.770 us; speedup 1.0000x reference)
//
#include <hip/hip_runtime.h>
#include <math.h>

#define T_STEPS 64
#define BATCH   256
#define NX      512
#define NH      512

// ---------------------------------------------------------------------------
// Kernel 1: P[r][h] = b1[h] + sum_k X[r][k] * W1[h][k]
//   r in [0, 16384), h in [0, 512), K = 512.
//   128x128 block tile, 8x8 per thread, BK=32, transposed LDS tiles so the
//   k-loop reads are conflict-free ds_read_b128.
// ---------------------------------------------------------------------------
__global__ __launch_bounds__(256) void gemm_p_kernel(
    const float* __restrict__ X,    // [16384][512]
    const float* __restrict__ W1,   // [512][512]
    const float* __restrict__ b1,   // [512]
    float* __restrict__ P)          // [16384][512]
{
    __shared__ float As[32][132];   // [k][m], pad 132 to spread banks
    __shared__ float Bs[32][132];   // [k][n]

    const int tid   = threadIdx.x;
    const int tx    = tid & 15;     // n direction
    const int ty    = tid >> 4;     // m direction
    const int rbase = blockIdx.x * 128;
    const int nbase = blockIdx.y * 128;

    float acc[8][8] = {};

    for (int kb = 0; kb < 512; kb += 32) {
        // Stage 128x32 tiles of X and W1, transposed into LDS.
#pragma unroll
        for (int i = 0; i < 4; ++i) {
            int lid = tid + i * 256;        // 0..1023
            int row = lid >> 3;             // 0..127
            int c4  = (lid & 7) << 2;       // 0,4,...,28
            float4 v = *(const float4*)&X[(size_t)(rbase + row) * 512 + kb + c4];
            As[c4 + 0][row] = v.x; As[c4 + 1][row] = v.y;
            As[c4 + 2][row] = v.z; As[c4 + 3][row] = v.w;
            float4 w = *(const float4*)&W1[(size_t)(nbase + row) * 512 + kb + c4];
            Bs[c4 + 0][row] = w.x; Bs[c4 + 1][row] = w.y;
            Bs[c4 + 2][row] = w.z; Bs[c4 + 3][row] = w.w;
        }
        __syncthreads();

#pragma unroll
        for (int k = 0; k < 32; ++k) {
            float av[8], bv[8];
            *(float4*)&av[0] = *(const float4*)&As[k][ty * 4];
            *(float4*)&av[4] = *(const float4*)&As[k][64 + ty * 4];
            *(float4*)&bv[0] = *(const float4*)&Bs[k][tx * 4];
            *(float4*)&bv[4] = *(const float4*)&Bs[k][64 + tx * 4];
#pragma unroll
            for (int i = 0; i < 8; ++i)
#pragma unroll
                for (int j = 0; j < 8; ++j)
                    acc[i][j] += av[i] * bv[j];
        }
        __syncthreads();
    }

    // Epilogue: add b1 and store.
    float bc[8];
#pragma unroll
    for (int j = 0; j < 4; ++j) {
        bc[j]     = b1[nbase + tx * 4 + j];
        bc[4 + j] = b1[nbase + 64 + tx * 4 + j];
    }
#pragma unroll
    for (int i = 0; i < 8; ++i) {
        int m = (i < 4) ? (ty * 4 + i) : (64 + ty * 4 + (i - 4));
        size_t rowoff = (size_t)(rbase + m) * 512 + nbase;
        float4 v0 = make_float4(acc[i][0] + bc[0], acc[i][1] + bc[1],
                                acc[i][2] + bc[2], acc[i][3] + bc[3]);
        float4 v1 = make_float4(acc[i][4] + bc[4], acc[i][5] + bc[5],
                                acc[i][6] + bc[6], acc[i][7] + bc[7]);
        *(float4*)&P[rowoff + tx * 4]      = v0;
        *(float4*)&P[rowoff + 64 + tx * 4] = v1;
    }
}

// ---------------------------------------------------------------------------
// Kernel 2: per-batch Gram matrix, strictly lower pairs only.
//   Gt[b][t][s] = dot(x[s,b,:], x[t,b,:])  for s < t.
//   One block per batch; X_b staged fully in LDS (64 x 516 floats = 129 KB).
// ---------------------------------------------------------------------------
__global__ __launch_bounds__(256) void gram_kernel(
    const float* __restrict__ X,    // [T][B][NX]
    float* __restrict__ Gt)         // [B][64][64]
{
    const int b   = blockIdx.x;
    const int tid = threadIdx.x;
    __shared__ float Xs[64][516];   // pad 516 (16B-aligned rows, banks spread)

    for (int idx = tid; idx < 64 * 128; idx += 256) {
        int t  = idx >> 7;
        int c4 = (idx & 127) << 2;
        float4 v = *(const float4*)&X[((size_t)t * BATCH + b) * NX + c4];
        *(float4*)&Xs[t][c4] = v;
    }
    __syncthreads();

    // 2016 pairs (s < t)
    for (int p = tid; p < 2016; p += 256) {
        int t = (int)((1.0f + sqrtf(1.0f + 8.0f * (float)p)) * 0.5f);
        while (t * (t - 1) / 2 > p) --t;
        while ((t + 1) * t / 2 <= p) ++t;
        int s = p - t * (t - 1) / 2;

        float sum = 0.f;
#pragma unroll 8
        for (int k4 = 0; k4 < 128; ++k4) {
            float4 a = *(const float4*)&Xs[s][k4 * 4];
            float4 c = *(const float4*)&Xs[t][k4 * 4];
            sum += a.x * c.x + a.y * c.y + a.z * c.z + a.w * c.w;
        }
        Gt[((size_t)b * 64 + t) * 64 + s] = sum;
    }
}

// ---------------------------------------------------------------------------
// Kernel 3: sequential scan, one block per batch (recurrences are
// batch-independent). 512 threads = one per hidden unit. Full h-history in
// LDS (128 KB). P aliases outH: P[t,b,h] is read at step t by thread h, then
// the same thread stores h_t to the same address.
// ---------------------------------------------------------------------------
__global__ __launch_bounds__(512) void scan_kernel(
    const float* __restrict__ P,    // [T][B][NH]  (== outH)
    const float* __restrict__ Gt,   // [B][64][64]
    const float* __restrict__ w2,   // [NH][2]
    const float* __restrict__ b2,   // [2]
    const float* __restrict__ w21,  // [NH][2]
    const float* __restrict__ lamp, // scalar
    const float* __restrict__ etap, // scalar
    float* __restrict__ outH,       // [T][B][NH]
    float* __restrict__ outY)       // [T][B][2]
{
    const int b = blockIdx.x;
    const int h = threadIdx.x;

    __shared__ float Hs[64][512];   // 128 KB history of h
    __shared__ float coeff[64];
    __shared__ float lampw[64];
    __shared__ float a2s[2];
    __shared__ float red[16];       // 8 waves x 2

    const float eta = etap[0];
    const float2 w21v = *(const float2*)&w21[2 * h];
    const float2 w2v  = *(const float2*)&w2[2 * h];

    if (h == 0) {
        float lc = fminf(lamp[0], 1.0f);
        float pw = 1.0f;
        for (int k = 0; k < 64; ++k) { lampw[k] = pw; pw *= lc; }
    }
    __syncthreads();

    float a2_0 = 0.f, a2_1 = 0.f;

    for (int t = 0; t < T_STEPS; ++t) {
        if (h < t)
            coeff[h] = eta * lampw[t - 1 - h] * Gt[((size_t)b * 64 + t) * 64 + h];
        __syncthreads();                                   // sync1

        float a1 = P[((size_t)t * BATCH + b) * NH + h]
                 + w21v.x * a2_0 + w21v.y * a2_1;
        int s = 0;
        for (; s + 3 < t; s += 4) {
            a1 += coeff[s]     * Hs[s][h]     + coeff[s + 1] * Hs[s + 1][h]
                + coeff[s + 2] * Hs[s + 2][h] + coeff[s + 3] * Hs[s + 3][h];
        }
        for (; s < t; ++s) a1 += coeff[s] * Hs[s][h];

        float hv = 1.0f / (1.0f + __expf(-a1));
        Hs[t][h] = hv;
        outH[((size_t)t * BATCH + b) * NH + h] = hv;

        // a2_new[y] = b2[y] + sum_h hv * w2[h][y]  (block reduction)
        float p0 = hv * w2v.x;
        float p1 = hv * w2v.y;
#pragma unroll
        for (int off = 32; off > 0; off >>= 1) {
            p0 += __shfl_down(p0, off);
            p1 += __shfl_down(p1, off);
        }
        int wave = h >> 6;
        if ((h & 63) == 0) { red[wave * 2] = p0; red[wave * 2 + 1] = p1; }
        __syncthreads();                                   // sync2

        if (h == 0) {
            float s0 = 0.f, s1 = 0.f;
#pragma unroll
            for (int w = 0; w < 8; ++w) { s0 += red[w * 2]; s1 += red[w * 2 + 1]; }
            s0 += b2[0]; s1 += b2[1];
            a2s[0] = s0; a2s[1] = s1;
            outY[((size_t)t * BATCH + b) * 2 + 0] = 1.0f / (1.0f + __expf(-s0));
            outY[((size_t)t * BATCH + b) * 2 + 1] = 1.0f / (1.0f + __expf(-s1));
        }
        __syncthreads();                                   // sync3
        a2_0 = a2s[0];
        a2_1 = a2s[1];
    }
}

// ---------------------------------------------------------------------------
extern "C" void kernel_launch(void* const* d_in, const int* in_sizes, int n_in,
                              void* d_out, int out_size, void* d_ws, size_t ws_size,
                              hipStream_t stream) {
    const float* x   = (const float*)d_in[0];
    const float* w1  = (const float*)d_in[1];
    const float* b1  = (const float*)d_in[2];
    const float* w2  = (const float*)d_in[3];
    const float* b2  = (const float*)d_in[4];
    const float* w21 = (const float*)d_in[5];
    const float* lam = (const float*)d_in[6];
    const float* eta = (const float*)d_in[7];

    float* outH = (float*)d_out;                       // [64*256*512], doubles as P
    float* outY = outH + (size_t)T_STEPS * BATCH * NH; // [64*256*2]
    float* Gt   = (float*)d_ws;                        // [256*64*64] = 4 MB

    gemm_p_kernel<<<dim3(128, 4), 256, 0, stream>>>(x, w1, b1, outH);
    gram_kernel<<<256, 256, 0, stream>>>(x, Gt);
    scan_kernel<<<256, 512, 0, stream>>>(outH, Gt, w2, b2, w21, lam, eta, outH, outY);
}

// Round 3
// 132.077 us; speedup vs baseline: 1.8608x; 1.8608x over previous
//
#include <hip/hip_runtime.h>
#include <math.h>

#define T_STEPS 64
#define BATCH   256
#define NX      512
#define NH      512

typedef short bf16x8 __attribute__((ext_vector_type(8)));
typedef float f32x4  __attribute__((ext_vector_type(4)));

// f32 -> bf16 round-to-nearest-even (bit trick, no NaN inputs here)
__device__ __forceinline__ unsigned short f2bf(float f) {
    union { float f; unsigned u; } v; v.f = f;
    unsigned r = v.u + 0x7fffu + ((v.u >> 16) & 1u);
    return (unsigned short)(r >> 16);
}

// ---------------------------------------------------------------------------
// Kernel 1: P[r][h] = b1[h] + sum_k X[r][k] * W1[h][k]   (bf16 MFMA, f32 acc)
//   M=16384, N=512, K=512. 128x128 block tile, 4 waves (2x2), each wave 64x64
//   = 4x4 fragments of 16x16x32. LDS holds bf16 tiles in fragment-lane order:
//   group g = ((ks*8+ms)*64+lane) stores 8 contiguous k-elems (16B) for
//   row ms*16+(lane&15), k = ks*32+(lane>>4)*8.  Writes and reads are both
//   lane-contiguous 16B -> conflict-free.
// ---------------------------------------------------------------------------
__global__ __launch_bounds__(256, 2) void gemm_bf16_kernel(
    const float* __restrict__ X,    // [16384][512]
    const float* __restrict__ W1,   // [512][512]
    const float* __restrict__ b1,   // [512]
    float* __restrict__ P)          // [16384][512]
{
    __shared__ unsigned short lds[16384];   // 32 KB: A = [0,8192), B = [8192,16384)

    const int tid  = threadIdx.x;
    const int lane = tid & 63;
    const int wave = tid >> 6;
    const int wm   = wave >> 1;     // 0..1 (m half)
    const int wn   = wave & 1;      // 0..1 (n half)
    const int rbase = blockIdx.x * 128;
    const int nbase = blockIdx.y * 128;

    f32x4 acc[4][4] = {};

    for (int kb = 0; kb < 512; kb += 64) {
        // ---- stage: 4 passes A, 4 passes B (each thread: float8 -> 8 bf16 -> b128 write)
#pragma unroll
        for (int i = 0; i < 8; ++i) {
            int g   = tid + (i & 3) * 256;          // 0..1023 fragment-group index
            int ks  = g >> 9;
            int ms  = (g >> 6) & 7;
            int l   = g & 63;
            int row = ms * 16 + (l & 15);
            int kof = kb + ks * 32 + (l >> 4) * 8;
            const float* src = (i < 4) ? &X[(size_t)(rbase + row) * 512 + kof]
                                       : &W1[(size_t)(nbase + row) * 512 + kof];
            float4 v0 = *(const float4*)src;
            float4 v1 = *(const float4*)(src + 4);
            unsigned p0 = (unsigned)f2bf(v0.x) | ((unsigned)f2bf(v0.y) << 16);
            unsigned p1 = (unsigned)f2bf(v0.z) | ((unsigned)f2bf(v0.w) << 16);
            unsigned p2 = (unsigned)f2bf(v1.x) | ((unsigned)f2bf(v1.y) << 16);
            unsigned p3 = (unsigned)f2bf(v1.z) | ((unsigned)f2bf(v1.w) << 16);
            int4 pk = make_int4((int)p0, (int)p1, (int)p2, (int)p3);
            *(int4*)&lds[((i < 4) ? 0 : 8192) + g * 8] = pk;
        }
        __syncthreads();

        // ---- compute: 2 k-slices x (4+4 ds_read_b128 -> 16 MFMA)
#pragma unroll
        for (int ks = 0; ks < 2; ++ks) {
            bf16x8 afr[4], bfr[4];
#pragma unroll
            for (int mf = 0; mf < 4; ++mf)
                afr[mf] = *(const bf16x8*)&lds[((ks * 8 + wm * 4 + mf) * 64 + lane) * 8];
#pragma unroll
            for (int nf = 0; nf < 4; ++nf)
                bfr[nf] = *(const bf16x8*)&lds[8192 + ((ks * 8 + wn * 4 + nf) * 64 + lane) * 8];
#pragma unroll
            for (int mf = 0; mf < 4; ++mf)
#pragma unroll
                for (int nf = 0; nf < 4; ++nf)
                    acc[mf][nf] = __builtin_amdgcn_mfma_f32_16x16x32_bf16(
                        afr[mf], bfr[nf], acc[mf][nf], 0, 0, 0);
        }
        __syncthreads();
    }

    // ---- epilogue: + b1, store.  C/D map: col = lane&15, row = (lane>>4)*4 + r
    float bc[4];
#pragma unroll
    for (int nf = 0; nf < 4; ++nf)
        bc[nf] = b1[nbase + wn * 64 + nf * 16 + (lane & 15)];
#pragma unroll
    for (int mf = 0; mf < 4; ++mf) {
#pragma unroll
        for (int nf = 0; nf < 4; ++nf) {
#pragma unroll
            for (int r = 0; r < 4; ++r) {
                int m = rbase + wm * 64 + mf * 16 + ((lane >> 4) << 2) + r;
                int n = nbase + wn * 64 + nf * 16 + (lane & 15);
                P[(size_t)m * 512 + n] = acc[mf][nf][r] + bc[nf];
            }
        }
    }
}

// ---------------------------------------------------------------------------
// Kernel 2: per-batch Gram, full 64x64 (only s<t is consumed).
//   4x4 register tiling: thread (a,bb): s-rows a*4+i (broadcast groups),
//   t-rows bb+16j (strided; row stride 516 floats -> stride mod 32 banks = 4,
//   worst 2-way conflict = free).
//   FIX vs round 2: Xs row length must hold all 512 columns (was 132 -> rows
//   aliased each other and overran the array -> garbage Gram).
// ---------------------------------------------------------------------------
__global__ __launch_bounds__(256) void gram_kernel(
    const float* __restrict__ X,    // [T][B][NX]
    float* __restrict__ Gt)         // [B][64][64]
{
    const int b   = blockIdx.x;
    const int tid = threadIdx.x;
    __shared__ float Xs[64][516];   // 132 KB, fits in 160 KB LDS

    for (int idx = tid; idx < 64 * 128; idx += 256) {
        int t  = idx >> 7;
        int c4 = (idx & 127) << 2;
        *(float4*)&Xs[t][c4] = *(const float4*)&X[((size_t)t * BATCH + b) * NX + c4];
    }
    __syncthreads();

    const int a  = tid >> 4;    // 0..15 -> s rows a*4..a*4+3
    const int bb = tid & 15;    // t rows bb, bb+16, bb+32, bb+48

    float acc[4][4] = {};
#pragma unroll 2
    for (int k = 0; k < 512; k += 4) {
        float4 sv[4], tv[4];
#pragma unroll
        for (int i = 0; i < 4; ++i) sv[i] = *(const float4*)&Xs[a * 4 + i][k];
#pragma unroll
        for (int j = 0; j < 4; ++j) tv[j] = *(const float4*)&Xs[bb + 16 * j][k];
#pragma unroll
        for (int i = 0; i < 4; ++i)
#pragma unroll
            for (int j = 0; j < 4; ++j)
                acc[i][j] += sv[i].x * tv[j].x + sv[i].y * tv[j].y
                           + sv[i].z * tv[j].z + sv[i].w * tv[j].w;
    }
#pragma unroll
    for (int j = 0; j < 4; ++j)
#pragma unroll
        for (int i = 0; i < 4; ++i)
            Gt[((size_t)b * 64 + (bb + 16 * j)) * 64 + (a * 4 + i)] = acc[i][j];
}

// ---------------------------------------------------------------------------
// Kernel 3: scan. One block per batch, 512 threads = one per hidden unit.
//   History kept in REGISTERS: hreg[s] = eta * lam^{-(s+1)} * h_s, so the
//   fast-weight term is lam^t * sum_s G[t][s]*hreg[s] (G loads are
//   block-uniform -> s_load + SGPR fmac). Full 64-step unroll for static
//   register indexing. One barrier per step; red[] double-buffered by parity.
// ---------------------------------------------------------------------------
__global__ __launch_bounds__(512) void scan_kernel(
    const float* __restrict__ P,    // [T][B][NH]  (== outH, aliased)
    const float* __restrict__ Gt,   // [B][64][64]
    const float* __restrict__ w2,   // [NH][2]
    const float* __restrict__ b2,   // [2]
    const float* __restrict__ w21,  // [NH][2]
    const float* __restrict__ lamp,
    const float* __restrict__ etap,
    float* __restrict__ outH,       // [T][B][NH]
    float* __restrict__ outY)       // [T][B][2]
{
    const int b = blockIdx.x;
    const int h = threadIdx.x;

    __shared__ float red[2][16];

    const float eta  = etap[0];
    const float lc   = fminf(lamp[0], 1.0f);
    const float rinv = 1.0f / lc;
    const float2 w21v = *(const float2*)&w21[2 * h];
    const float2 w2v  = *(const float2*)&w2[2 * h];
    const float b20 = b2[0], b21 = b2[1];
    const float* grow = Gt + (size_t)b * 4096;

    float hreg[64];
    float a2x = 0.f, a2y = 0.f;
    float lamt = 1.0f;          // lam^t
    float sc   = eta * rinv;    // eta * lam^{-(t+1)}

#pragma unroll
    for (int t = 0; t < T_STEPS; ++t) {
        const float* gr = grow + t * 64;
        float ac[4] = {0.f, 0.f, 0.f, 0.f};
#pragma unroll
        for (int s = 0; s < t; ++s)
            ac[s & 3] = fmaf(gr[s], hreg[s], ac[s & 3]);

        float a1 = P[(size_t)t * (BATCH * NH) + (size_t)b * NH + h]
                 + w21v.x * a2x + w21v.y * a2y
                 + lamt * ((ac[0] + ac[1]) + (ac[2] + ac[3]));
        float hv = 1.0f / (1.0f + __expf(-a1));

        outH[(size_t)t * (BATCH * NH) + (size_t)b * NH + h] = hv;
        hreg[t] = sc * hv;

        // a2_{t+1} = b2 + h_t . w2  (block reduction)
        float p0 = hv * w2v.x;
        float p1 = hv * w2v.y;
#pragma unroll
        for (int off = 32; off > 0; off >>= 1) {
            p0 += __shfl_down(p0, off);
            p1 += __shfl_down(p1, off);
        }
        if ((h & 63) == 0) {
            red[t & 1][(h >> 6) * 2]     = p0;
            red[t & 1][(h >> 6) * 2 + 1] = p1;
        }
        __syncthreads();

        float s0 = b20, s1 = b21;
#pragma unroll
        for (int w = 0; w < 8; ++w) {
            s0 += red[t & 1][2 * w];
            s1 += red[t & 1][2 * w + 1];
        }
        a2x = s0; a2y = s1;
        if (h == 0) {
            outY[((size_t)t * BATCH + b) * 2 + 0] = 1.0f / (1.0f + __expf(-s0));
            outY[((size_t)t * BATCH + b) * 2 + 1] = 1.0f / (1.0f + __expf(-s1));
        }
        lamt *= lc;
        sc   *= rinv;
    }
}

// ---------------------------------------------------------------------------
extern "C" void kernel_launch(void* const* d_in, const int* in_sizes, int n_in,
                              void* d_out, int out_size, void* d_ws, size_t ws_size,
                              hipStream_t stream) {
    const float* x   = (const float*)d_in[0];
    const float* w1  = (const float*)d_in[1];
    const float* b1  = (const float*)d_in[2];
    const float* w2  = (const float*)d_in[3];
    const float* b2  = (const float*)d_in[4];
    const float* w21 = (const float*)d_in[5];
    const float* lam = (const float*)d_in[6];
    const float* eta = (const float*)d_in[7];

    float* outH = (float*)d_out;                       // [64*256*512], doubles as P
    float* outY = outH + (size_t)T_STEPS * BATCH * NH; // [64*256*2]
    float* Gt   = (float*)d_ws;                        // [256*64*64] = 4 MB

    gemm_bf16_kernel<<<dim3(128, 4), 256, 0, stream>>>(x, w1, b1, outH);
    gram_kernel<<<256, 256, 0, stream>>>(x, Gt);
    scan_kernel<<<256, 512, 0, stream>>>(outH, Gt, w2, b2, w21, lam, eta, outH, outY);
}